// Round 7
// baseline (180.134 us; speedup 1.0000x reference)
//
#include <hip/hip_runtime.h>
#include <stdint.h>

#define NCLS    80
#define NA_TOT  8400     // 6400 + 1600 + 400
#define NBATCH  32
#define MAXDET  300
#define SSORT   2048
#define RANKCAP 1536
#define CONFTHR 0.001f

// ---------------------------------------------------------------------------
// Bit-exact reconstruction of XLA:CPU f32 exp (Eigen/Cephes pexp, no FMA) and
// logistic = 1/(1+exp(-x)). Validated absmax==0.0 rounds 1-6. DO NOT TOUCH.
// ---------------------------------------------------------------------------
__device__ __forceinline__ float xla_expf(float in) {
  const float exp_hi = 88.3762626647950f;
  const float exp_lo = -88.3762626647949f;
  const float LOG2EF = 1.44269504088896341f;
  const float C1 = 0.693359375f;
  const float C2 = -2.12194440e-4f;
  const float p0 = 1.9875691500E-4f, p1 = 1.3981999507E-3f, p2 = 8.3334519073E-3f;
  const float p3 = 4.1665795894E-2f, p4 = 1.6666665459E-1f, p5 = 5.0000001201E-1f;
  float x = fminf(fmaxf(in, exp_lo), exp_hi);
  float fx = floorf(__fadd_rn(__fmul_rn(x, LOG2EF), 0.5f));
  float tmp = __fmul_rn(C1, fx);
  float z   = __fmul_rn(C2, fx);
  x = __fsub_rn(x, tmp);
  x = __fsub_rn(x, z);
  float y = __fadd_rn(__fmul_rn(x, p0), p1);
  y = __fadd_rn(__fmul_rn(y, x), p2);
  y = __fadd_rn(__fmul_rn(y, x), p3);
  y = __fadd_rn(__fmul_rn(y, x), p4);
  y = __fadd_rn(__fmul_rn(y, x), p5);
  y = __fadd_rn(__fmul_rn(y, __fmul_rn(x, x)), x);
  y = __fadd_rn(1.0f, y);
  int m = (int)fx;
  float s = __uint_as_float((uint32_t)(m + 127) << 23);
  float r = __fmul_rn(y, s);
  return fmaxf(r, in);
}

__device__ __forceinline__ float xla_sigmoid(float v) {
  float e = xla_expf(-v);
  float den = __fadd_rn(1.0f, e);
  return 1.0f / den;
}

// ---------------------------------------------------------------------------
// Kernel 1: decode, 2 anchors/thread, float2 loads, explicit 9-stage
// ping-pong prefetch (load stage s+1 while computing stage s).
// Per-anchor FP sequences bit-identical to validated r1.
// Level boundaries (6400/8000/8400) are even -> a pair never straddles.
// ---------------------------------------------------------------------------
__global__ __launch_bounds__(256, 3) void yolo_decode_kernel(
    const float* __restrict__ f0, const float* __restrict__ f1,
    const float* __restrict__ f2,
    float4* __restrict__ oboxes, float* __restrict__ oconf,
    float* __restrict__ oclsf) {
  int t = blockIdx.x * 256 + threadIdx.x;     // 134400 threads = 525 blocks
  int b = t / 4200;
  int r = t - b * 4200;
  int a = r * 2;                              // global anchor (pair start)

  const float* base; int W, ai; float stridef;
  if (a < 6400)      { base = f0 + (size_t)b * (144 * 6400); W = 80; ai = a;        stridef = 8.0f;  }
  else if (a < 8000) { base = f1 + (size_t)b * (144 * 1600); W = 40; ai = a - 6400; stridef = 16.0f; }
  else               { base = f2 + (size_t)b * (144 * 400);  W = 20; ai = a - 8000; stridef = 32.0f; }
  int Alvl = W * W;
  const float* cp = base + ai;                // 8B-aligned (ai even, Alvl even)

  float2 A[16], B[16];
  auto load16 = [&](float2* dst, int chbase) {
    #pragma unroll
    for (int k2 = 0; k2 < 16; ++k2)
      dst[k2] = *reinterpret_cast<const float2*>(cp + (size_t)(chbase + k2) * Alvl);
  };

  float lt[4][2];
  auto dflSide = [&](const float2* buf, int fs) {
    #pragma unroll
    for (int j = 0; j < 2; ++j) {
      float mx = -INFINITY;
      #pragma unroll
      for (int rr = 0; rr < 16; ++rr) {
        float v = j ? buf[rr].y : buf[rr].x;
        mx = fmaxf(mx, v);
      }
      float e[16]; float ssum = 0.0f;
      #pragma unroll
      for (int rr = 0; rr < 16; ++rr) {
        float v = j ? buf[rr].y : buf[rr].x;
        e[rr] = xla_expf(__fsub_rn(v, mx));
        ssum = __fadd_rn(ssum, e[rr]);
      }
      float acc = 0.0f;
      #pragma unroll
      for (int rr = 0; rr < 16; ++rr) {
        float p = e[rr] / ssum;
        acc = __fadd_rn(acc, __fmul_rn(p, (float)rr));
      }
      lt[fs][j] = acc;
    }
  };

  float best[2] = {-INFINITY, -INFINITY}, second[2] = {-INFINITY, -INFINITY};
  int bi[2] = {0, 0};
  auto clsScan = [&](const float2* buf, int kbase) {
    #pragma unroll
    for (int k2 = 0; k2 < 16; ++k2) {
      #pragma unroll
      for (int j = 0; j < 2; ++j) {
        float v = j ? buf[k2].y : buf[k2].x;
        if (v > best[j])        { second[j] = best[j]; best[j] = v; bi[j] = kbase + k2; }
        else if (v > second[j]) { second[j] = v; }
      }
    }
  };

  // ---- 9-stage ping-pong: prefetch next while computing current ----
  load16(A, 0);
  load16(B, 16);  dflSide(A, 0);
  load16(A, 32);  dflSide(B, 1);
  load16(B, 48);  dflSide(A, 2);
  load16(A, 64);  dflSide(B, 3);
  load16(B, 80);  clsScan(A, 0);
  load16(A, 96);  clsScan(B, 16);
  load16(B, 112); clsScan(A, 32);
  load16(A, 128); clsScan(B, 48);
  clsScan(A, 64);

  // ---- finalize both anchors (bit-exact r1 sequences) ----
  #pragma unroll
  for (int j = 0; j < 2; ++j) {
    float conf; int cls = bi[j];
    if (__fsub_rn(best[j], second[j]) < 1e-4f || best[j] > 5.0f) {
      // exact slow path (rare): identical to validated r1 80-sigmoid scan
      const float* cpj = cp + j;
      float bs = -INFINITY; int bj = 0;
      for (int k = 0; k < NCLS; ++k) {
        float v = cpj[(size_t)(64 + k) * Alvl];
        float s = xla_sigmoid(v);
        if (s > bs) { bs = s; bj = k; }
      }
      conf = bs; cls = bj;
    } else {
      conf = xla_sigmoid(best[j]);
    }

    int aij = ai + j;
    float ax = __fadd_rn((float)(aij % W), 0.5f);
    float ay = __fadd_rn((float)(aij / W), 0.5f);
    float x1 = __fsub_rn(ax, lt[0][j]);
    float y1 = __fsub_rn(ay, lt[1][j]);
    float x2 = __fadd_rn(ax, lt[2][j]);
    float y2 = __fadd_rn(ay, lt[3][j]);
    float cx = __fmul_rn(__fadd_rn(x1, x2), 0.5f);
    float cy = __fmul_rn(__fadd_rn(y1, y2), 0.5f);
    float w  = __fsub_rn(x2, x1);
    float h  = __fsub_rn(y2, y1);

    int to = b * NA_TOT + a + j;
    oboxes[to] = make_float4(__fmul_rn(cx, stridef), __fmul_rn(cy, stridef),
                             __fmul_rn(w, stridef),  __fmul_rn(h, stridef));
    conf = (conf > CONFTHR) ? conf : 0.0f;
    oconf[to] = conf;
    oclsf[to] = (float)cls;
  }
}

// ---------------------------------------------------------------------------
// Kernel 2: per-image exact top-1024 select + rank (validated r5, unchanged).
// ---------------------------------------------------------------------------
struct __align__(16) K2Lds {
  unsigned long long sortkeys[SSORT];   // 16384 B (offset 0: 16B-aligned)
  unsigned confL[NA_TOT];               // 33600 B
  unsigned hist[16][257];               // 16448 B (per-wave, padded)
  unsigned tot[257];
  unsigned Tarr[257];
  unsigned long long alive[16];
  unsigned clsCnt[NCLS];
};                                      // ~69 KB

__global__ __launch_bounds__(1024) void yolo_select_kernel(
    const float4* __restrict__ boxes, const float* __restrict__ conf,
    const float* __restrict__ clsf,
    float* __restrict__ g_rowd, unsigned long long* __restrict__ g_alive,
    unsigned* __restrict__ g_clsc) {
  __shared__ K2Lds u;
  __shared__ unsigned s_need, s_prefix, s_found, s_B, s_scnt, s_cut, s_done;
  int b    = blockIdx.x;
  int tid  = threadIdx.x;
  int lane = tid & 63;
  int wv   = tid >> 6;
  const unsigned* confu = (const unsigned*)conf + (size_t)b * NA_TOT;

  // ---- P0: stage conf bits; zero outputs ----
  for (int i = tid; i < NA_TOT; i += 1024) u.confL[i] = confu[i];
  {
    float4 z4 = make_float4(0.f, 0.f, 0.f, 0.f);
    float4* gr = (float4*)(g_rowd + (size_t)b * 1024 * 8);
    for (int k = tid; k < 2048; k += 1024) gr[k] = z4;   // 1024 rows x 32 B
  }
  if (tid < NCLS) u.clsCnt[tid] = 0;
  if (tid < 16)   u.alive[tid]  = 0ull;
  if (tid == 0) { s_need = 1024; s_prefix = 0; s_cut = 0; s_done = 0; s_scnt = 0; }
  __syncthreads();

  // ---- P1: adaptive 8-bit radix descent (exact selcnt bound) ----
  for (int lv = 0; lv < 4; ++lv) {
    __syncthreads();
    if (s_done) break;                          // uniform
    for (int i = tid; i < 16 * 257; i += 1024) ((unsigned*)u.hist)[i] = 0;
    if (tid == 0) { s_found = 0; s_B = 0; }
    __syncthreads();
    unsigned pfx = s_prefix;
    for (int it = 0; it < 9; ++it) {
      int i = tid + it * 1024;
      unsigned c = (i < NA_TOT) ? u.confL[i] : 0u;
      bool in; unsigned bin;
      if (lv == 0)      { in = true;                bin = c >> 23; }
      else if (lv == 1) { in = ((c >> 23) == pfx);  bin = (c >> 15) & 0xFF; }
      else if (lv == 2) { in = ((c >> 15) == pfx);  bin = (c >> 7) & 0xFF; }
      else              { in = ((c >> 7)  == pfx);  bin = c & 0x7F; }
      bool act = (c != 0) && in;
      unsigned long long ab = __ballot(act);
      if (ab) {                                 // wave-uniform branch
        int fl = __ffsll(ab) - 1;
        unsigned fbin = __shfl(bin, fl);
        unsigned long long same = __ballot(act && (bin == fbin));
        if (same == ab) {                       // all active lanes same bin
          if (lane == fl) atomicAdd(&u.hist[wv][fbin], (unsigned)__popcll(ab));
        } else if (act) {
          atomicAdd(&u.hist[wv][bin], 1u);
        }
      }
    }
    __syncthreads();
    if (tid < 256) {                            // reduce 16 wave-hists
      unsigned s = 0;
      #pragma unroll
      for (int q = 0; q < 16; ++q) s += u.hist[q][tid];
      u.tot[tid] = s;
    }
    __syncthreads();
    if (tid < 64) {                             // suffix scan (4 chunks of 64)
      unsigned carry = 0;
      if (tid == 0) u.Tarr[256] = 0;
      for (int ch = 3; ch >= 0; --ch) {
        int bb = ch * 64 + tid;
        unsigned v = u.tot[bb];
        #pragma unroll
        for (int off = 1; off < 64; off <<= 1) {
          unsigned t2 = __shfl_down(v, off);
          if (tid + off < 64) v += t2;
        }
        u.Tarr[bb] = v + carry;
        carry += __shfl(v, 0);
      }
    }
    __syncthreads();
    unsigned need = s_need;
    if (tid < 256) {
      unsigned h = u.tot[tid];
      if (h > 0 && u.Tarr[tid + 1] < need && u.Tarr[tid + 1] + h >= need) {
        s_B = (unsigned)tid; s_found = 1;       // unique writer (T monotone)
      }
    }
    __syncthreads();
    if (tid == 0) {
      if (!s_found) { s_cut = 1; s_done = 1; }  // <1024 nonzero total (lv0)
      else {
        unsigned B = s_B;
        unsigned selcnt = (1024u - need) + u.Tarr[B];  // exact: committed + >=binB
        if (selcnt <= (unsigned)RANKCAP || lv == 3) {
          s_done = 1;
          if (lv == 0)      s_cut = B << 23;
          else if (lv == 1) s_cut = (s_prefix << 23) | (B << 15);
          else if (lv == 2) s_cut = (s_prefix << 15) | (B << 7);
          else              s_cut = (s_prefix << 7)  | B;
        } else {
          s_need   = need - u.Tarr[B + 1];
          s_prefix = (s_prefix << 8) | B;
        }
      }
    }
  }
  __syncthreads();

  // ---- P2: ballot-aggregated compact ----
  unsigned cut = s_cut;
  for (int it = 0; it < 9; ++it) {
    int i = tid + it * 1024;
    unsigned c = (i < NA_TOT) ? u.confL[i] : 0u;
    bool sel = (c != 0 && c >= cut);
    unsigned long long bal = __ballot(sel);
    unsigned base2 = 0;
    if (lane == 0 && bal) base2 = atomicAdd(&s_scnt, (unsigned)__popcll(bal));
    base2 = __shfl(base2, 0);
    if (sel) {
      unsigned p = base2 + (unsigned)__popcll(bal & ((1ull << lane) - 1ull));
      if (p < SSORT)
        u.sortkeys[p] = ((unsigned long long)c << 32) |
                        (unsigned long long)(0xFFFFFFFFu - (unsigned)i);
    }
  }
  __syncthreads();
  unsigned scnt = s_scnt; if (scnt > SSORT) scnt = SSORT;
  unsigned snp = (scnt + 1u) & ~1u;
  if (tid == 0 && (scnt & 1u)) u.sortkeys[scnt] = 0ull;  // pad for b128
  __syncthreads();

  // ---- P3: rank-by-count (b128 broadcast reads) + scatter to global ----
  for (unsigned e = tid; e < scnt; e += 1024) {
    unsigned long long mykey = u.sortkeys[e];
    unsigned r = 0;
    #pragma unroll 4
    for (unsigned j = 0; j < snp; j += 2) {
      ulonglong2 kk = *reinterpret_cast<const ulonglong2*>(&u.sortkeys[j]);
      r += (kk.x > mykey) ? 1u : 0u;
      r += (kk.y > mykey) ? 1u : 0u;
    }
    if (r < 1024) {                             // == lax.top_k truncation
      unsigned a = 0xFFFFFFFFu - (unsigned)(mykey & 0xFFFFFFFFull);
      float4 cb = boxes[(size_t)b * NA_TOT + a];
      float cls = clsf[(size_t)b * NA_TOT + a];
      float* rd = g_rowd + ((size_t)b * 1024 + r) * 8;
      rd[0] = cb.x; rd[1] = cb.y; rd[2] = cb.z; rd[3] = cb.w;
      rd[4] = __uint_as_float((unsigned)(mykey >> 32));
      rd[5] = cls;
      atomicOr(&u.alive[r >> 6], 1ull << (r & 63));
      atomicAdd(&u.clsCnt[(int)cls], 1u);
    }
  }
  __syncthreads();

  if (tid < 16)   g_alive[b * 16 + tid] = u.alive[tid];
  if (tid < NCLS) g_clsc[b * NCLS + tid] = u.clsCnt[tid];
}

// ---------------------------------------------------------------------------
// Kernel 3: per-image NMS (validated r5, unchanged): swizzled suppression-bit
// rows + single-wave greedy walk. Exact reference-scan semantics.
// ---------------------------------------------------------------------------
struct K3Lds {
  unsigned long long rows[1024][16];    // 131072 B, col-swizzled: phys = w^(r&15)
  float    rowdata[1024][6];            //  24576 B
  unsigned list[1024];                  //   4096 B
  unsigned clsCnt[NCLS];
  unsigned clsBase[NCLS];
  unsigned clsCur[NCLS];
  unsigned long long alive[16];
};                                      // ~160.9 KB

__global__ __launch_bounds__(1024) void yolo_nms_kernel(
    const float* __restrict__ g_rowd, const unsigned long long* __restrict__ g_alive,
    const unsigned* __restrict__ g_clsc, float* __restrict__ out) {
  __shared__ K3Lds u;
  __shared__ unsigned s_efinal;
  int b    = blockIdx.x;
  int tid  = threadIdx.x;
  int lane = tid & 63;

  // ---- load rowdata / alive / clsCnt; zero rows (linear = conflict-free) ----
  {
    const float4* gr = (const float4*)(g_rowd + ((size_t)b * 1024 + tid) * 8);
    float4 v0 = gr[0];
    float4 v1 = gr[1];
    u.rowdata[tid][0] = v0.x; u.rowdata[tid][1] = v0.y;
    u.rowdata[tid][2] = v0.z; u.rowdata[tid][3] = v0.w;
    u.rowdata[tid][4] = v1.x; u.rowdata[tid][5] = v1.y;
  }
  if (tid < 16)   u.alive[tid]  = g_alive[b * 16 + tid];
  if (tid < NCLS) u.clsCnt[tid] = g_clsc[b * NCLS + tid];
  {
    unsigned long long* flat = &u.rows[0][0];
    for (int k = tid; k < 1024 * 16; k += 1024) flat[k] = 0ull;
  }
  if (tid == 0) s_efinal = 0;
  __syncthreads();

  if (tid == 0) {
    unsigned acc = 0;
    for (int c2 = 0; c2 < NCLS; ++c2) {
      u.clsBase[c2] = acc; u.clsCur[c2] = acc; acc += u.clsCnt[c2];
    }
  }
  __syncthreads();

  // ---- per-class candidate lists ----
  bool valid = (u.alive[tid >> 6] >> (tid & 63)) & 1ull;
  float mycls = u.rowdata[tid][5];
  if (valid) {
    unsigned p = atomicAdd(&u.clsCur[(int)mycls], 1u);
    u.list[p] = (unsigned)tid;
  }
  __syncthreads();

  // ---- suppression-bit rows (same-class pairs; swizzled column writes) ----
  if (valid) {
    float bx0 = u.rowdata[tid][0], by0 = u.rowdata[tid][1];
    float bw0 = u.rowdata[tid][2], bh0 = u.rowdata[tid][3];
    int c = (int)mycls;
    unsigned base = u.clsBase[c], cnt = u.clsCnt[c];
    float off = __fmul_rn(mycls, 7680.0f);
    float hw  = __fmul_rn(bw0, 0.5f), hh = __fmul_rn(bh0, 0.5f);
    float wx1 = __fadd_rn(__fsub_rn(bx0, hw), off);
    float wy1 = __fadd_rn(__fsub_rn(by0, hh), off);
    float wx2 = __fadd_rn(__fadd_rn(bx0, hw), off);
    float wy2 = __fadd_rn(__fadd_rn(by0, hh), off);
    float a1  = __fmul_rn(__fsub_rn(wx2, wx1), __fsub_rn(wy2, wy1));
    int sw = tid & 15;
    for (unsigned l = 0; l < cnt; ++l) {
      int j = (int)u.list[base + l];
      float jx = u.rowdata[j][0], jy = u.rowdata[j][1];
      float jw = u.rowdata[j][2], jh = u.rowdata[j][3];
      float jhw = __fmul_rn(jw, 0.5f), jhh = __fmul_rn(jh, 0.5f);
      float jx1 = __fadd_rn(__fsub_rn(jx, jhw), off);
      float jy1 = __fadd_rn(__fsub_rn(jy, jhh), off);
      float jx2 = __fadd_rn(__fadd_rn(jx, jhw), off);
      float jy2 = __fadd_rn(__fadd_rn(jy, jhh), off);
      float ltx = fmaxf(wx1, jx1), lty = fmaxf(wy1, jy1);
      float rbx = fminf(wx2, jx2), rby = fminf(wy2, jy2);
      float iw = fmaxf(__fsub_rn(rbx, ltx), 0.0f);
      float ih = fmaxf(__fsub_rn(rby, lty), 0.0f);
      float inter = __fmul_rn(iw, ih);
      float a2 = __fmul_rn(__fsub_rn(jx2, jx1), __fsub_rn(jy2, jy1));
      float den = __fadd_rn(__fsub_rn(__fadd_rn(a1, a2), inter), 1e-7f);
      float iou = inter / den;
      if (iou > 0.7f)
        u.rows[tid][(j >> 6) ^ sw] |= (1ull << (j & 63));
    }
  }
  __syncthreads();

  // ---- single-wave greedy walk ----
  float* orow = out + (size_t)b * (MAXDET * 6);
  if (tid < 64) {
    unsigned long long am = (lane < 16) ? u.alive[lane] : 0ull;
    int e = 0;
    while (e < MAXDET) {
      unsigned long long bal = __ballot(am != 0ull);
      if (bal == 0ull) break;
      int f    = __ffsll((unsigned long long)bal) - 1;
      int myb  = __ffsll((unsigned long long)am) - 1;
      int bitp = __shfl(myb, f);
      int r    = f * 64 + bitp;                 // winner rank (uniform)
      if (lane < 6) orow[e * 6 + lane] = u.rowdata[r][lane];
      unsigned long long rowv =
          (lane < 16) ? u.rows[r][lane ^ (r & 15)] : 0ull;  // de-swizzle
      am &= ~rowv;      // winner self-suppresses via own row bit, as reference
      ++e;
    }
    if (tid == 0) s_efinal = (unsigned)e;
  }
  __syncthreads();

  // ---- zero-fill remaining output rows ----
  for (int i = (int)s_efinal * 6 + tid; i < MAXDET * 6; i += 1024)
    orow[i] = 0.0f;
}

extern "C" void kernel_launch(void* const* d_in, const int* in_sizes, int n_in,
                              void* d_out, int out_size, void* d_ws, size_t ws_size,
                              hipStream_t stream) {
  const float* f0 = (const float*)d_in[0];
  const float* f1 = (const float*)d_in[1];
  const float* f2 = (const float*)d_in[2];
  float* out = (float*)d_out;

  char* ws = (char*)d_ws;
  float4* boxes = (float4*)ws;                                       // 4,300,800
  float*  conf  = (float*)(ws + (size_t)NBATCH * NA_TOT * 16);       // 1,075,200
  float*  clsf  = (float*)(ws + (size_t)NBATCH * NA_TOT * 20);       // 1,075,200
  float*  rowd  = (float*)(ws + (size_t)NBATCH * NA_TOT * 24);       // 1,048,576
  unsigned long long* aliv =
      (unsigned long long*)(ws + (size_t)NBATCH * NA_TOT * 24 + 1048576);  // 4 KB
  unsigned* clsc =
      (unsigned*)(ws + (size_t)NBATCH * NA_TOT * 24 + 1048576 + 4096);     // 10 KB

  yolo_decode_kernel<<<525, 256, 0, stream>>>(f0, f1, f2, boxes, conf, clsf);
  yolo_select_kernel<<<NBATCH, 1024, 0, stream>>>(boxes, conf, clsf,
                                                  rowd, aliv, clsc);
  yolo_nms_kernel<<<NBATCH, 1024, 0, stream>>>(rowd, aliv, clsc, out);
}

// Round 8
// 170.092 us; speedup vs baseline: 1.0590x; 1.0590x over previous
//
#include <hip/hip_runtime.h>
#include <stdint.h>

#define NCLS    80
#define NA_TOT  8400     // 6400 + 1600 + 400
#define NBATCH  32
#define MAXDET  300
#define SSORT   2048
#define RANKCAP 1536
#define CONFTHR 0.001f
#define BLKS_PER_IMG 34   // 25 (L0) + 7 (L1, clamped) + 2 (L2, clamped)

// ---------------------------------------------------------------------------
// Bit-exact reconstruction of XLA:CPU f32 exp (Eigen/Cephes pexp, no FMA) and
// logistic = 1/(1+exp(-x)). Validated absmax==0.0 rounds 1-7. DO NOT TOUCH.
// ---------------------------------------------------------------------------
__device__ __forceinline__ float xla_expf(float in) {
  const float exp_hi = 88.3762626647950f;
  const float exp_lo = -88.3762626647949f;
  const float LOG2EF = 1.44269504088896341f;
  const float C1 = 0.693359375f;
  const float C2 = -2.12194440e-4f;
  const float p0 = 1.9875691500E-4f, p1 = 1.3981999507E-3f, p2 = 8.3334519073E-3f;
  const float p3 = 4.1665795894E-2f, p4 = 1.6666665459E-1f, p5 = 5.0000001201E-1f;
  float x = fminf(fmaxf(in, exp_lo), exp_hi);
  float fx = floorf(__fadd_rn(__fmul_rn(x, LOG2EF), 0.5f));
  float tmp = __fmul_rn(C1, fx);
  float z   = __fmul_rn(C2, fx);
  x = __fsub_rn(x, tmp);
  x = __fsub_rn(x, z);
  float y = __fadd_rn(__fmul_rn(x, p0), p1);
  y = __fadd_rn(__fmul_rn(y, x), p2);
  y = __fadd_rn(__fmul_rn(y, x), p3);
  y = __fadd_rn(__fmul_rn(y, x), p4);
  y = __fadd_rn(__fmul_rn(y, x), p5);
  y = __fadd_rn(__fmul_rn(y, __fmul_rn(x, x)), x);
  y = __fadd_rn(1.0f, y);
  int m = (int)fx;
  float s = __uint_as_float((uint32_t)(m + 127) << 23);
  float r = __fmul_rn(y, s);
  return fmaxf(r, in);
}

__device__ __forceinline__ float xla_sigmoid(float v) {
  float e = xla_expf(-v);
  float den = __fadd_rn(1.0f, e);
  return 1.0f / den;
}

__device__ __forceinline__ void gload_lds16(const float* gp, float* lp) {
  __builtin_amdgcn_global_load_lds(
      (const __attribute__((address_space(1))) void*)gp,
      (__attribute__((address_space(3))) void*)lp, 16, 0, 0);
}

// ---------------------------------------------------------------------------
// Kernel 1: pipelined decode. Block = 256 threads = 4 tiles x 64 anchors.
// Double-buffered LDS [144][64] (linear, global_load_lds direct), source-
// side XOR swizzle (reader: c*64 + (idx ^ (((c>>4)&3)<<4)) -> 2-way max).
// Per tile: issue next tile's loads -> compute current -> vmcnt(0)+s_barrier
// (raw barrier: __syncthreads would drain the async queue). Per-anchor FP
// sequences identical to validated r4 worker code.
// ---------------------------------------------------------------------------
__global__ __launch_bounds__(256) void yolo_decode_kernel(
    const float* __restrict__ f0, const float* __restrict__ f1,
    const float* __restrict__ f2,
    float4* __restrict__ oboxes, float* __restrict__ oconf,
    float* __restrict__ oclsf) {
  __shared__ float sm[2][144 * 64];             // 73,728 B
  int bx  = blockIdx.x;
  int b   = bx / BLKS_PER_IMG;
  int r   = bx - b * BLKS_PER_IMG;
  int tid = threadIdx.x;
  int lane = tid & 63;
  int wv   = tid >> 6;

  const float* base; int Alvl, a0blk, W, lvlbase; float stridef;
  if (r < 25)      { base = f0 + (size_t)b * (144 * 6400); W = 80; Alvl = 6400;
                     a0blk = r * 256; stridef = 8.0f; lvlbase = 0; }
  else if (r < 32) { base = f1 + (size_t)b * (144 * 1600); W = 40; Alvl = 1600;
                     int a = (r - 25) * 256; a0blk = (a + 256 <= 1600) ? a : 1344;
                     stridef = 16.0f; lvlbase = 6400; }
  else             { base = f2 + (size_t)b * (144 * 400);  W = 20; Alvl = 400;
                     a0blk = (r == 32) ? 0 : 144; stridef = 32.0f; lvlbase = 8000; }

  // ---- stage tile k into buffer q: 9 x gload_lds(16B) per wave ----
  auto STAGE = [&](int q, int k) {
    int a0t = a0blk + k * 64;
    float* lb = &sm[q][0];
    #pragma unroll
    for (int qq = 0; qq < 9; ++qq) {
      int chunk = wv * 9 + qq;                  // 0..35 (4 ch x 64 anchors each)
      int c     = chunk * 4 + (lane >> 4);
      int s     = (c >> 4) & 3;
      int idx4  = (lane & 15) ^ (s << 2);       // source-side swizzle (16B units)
      const float* gp = base + (size_t)c * Alvl + a0t + idx4 * 4;
      gload_lds16(gp, lb + chunk * 256);        // lane l -> lds + chunk*1024 + l*16
    }
  };

  // ---- compute tile k from buffer q (r4 worker code, swizzled reads) ----
  auto COMPUTE = [&](int q, int k) {
    const float* S = &sm[q][0];
    int idx = tid >> 2;                         // anchor in tile (0..63)
    int w   = tid & 3;                          // worker
    int ai  = a0blk + k * 64 + idx;             // within-level anchor
    float ax = __fadd_rn((float)(ai % W), 0.5f);
    float ay = __fadd_rn((float)(ai / W), 0.5f);

    // DFL side w (bit-exact r1/r4 sequence)
    int sidx = idx ^ (w << 4);                  // s(c)=w for c=w*16+rr
    float d[16];
    float mx = -INFINITY;
    #pragma unroll
    for (int rr = 0; rr < 16; ++rr) {
      d[rr] = S[(w * 16 + rr) * 64 + sidx];
      mx = fmaxf(mx, d[rr]);
    }
    float e[16]; float ssum = 0.0f;
    #pragma unroll
    for (int rr = 0; rr < 16; ++rr) {
      e[rr] = xla_expf(__fsub_rn(d[rr], mx));
      ssum = __fadd_rn(ssum, e[rr]);
    }
    float acc = 0.0f;
    #pragma unroll
    for (int rr = 0; rr < 16; ++rr) {
      float p = e[rr] / ssum;
      acc = __fadd_rn(acc, __fmul_rn(p, (float)rr));
    }

    int l0 = lane & ~3;
    float lt0 = __shfl(acc, l0 + 0);
    float lt1 = __shfl(acc, l0 + 1);
    float lt2 = __shfl(acc, l0 + 2);
    float lt3 = __shfl(acc, l0 + 3);

    // class top-2, 20 classes per worker (ascending, strict >)
    float best = -INFINITY, second = -INFINITY; int bi = 0;
    #pragma unroll 5
    for (int kk = 0; kk < 20; ++kk) {
      int c = 64 + w * 20 + kk;
      float v = S[c * 64 + (idx ^ (((c >> 4) & 3) << 4))];
      if (v > best)        { second = best; best = v; bi = w * 20 + kk; }
      else if (v > second) { second = v; }
    }
    float gb = __shfl(best, l0 + 0), gs = __shfl(second, l0 + 0);
    int   gi = __shfl(bi,   l0 + 0);
    #pragma unroll
    for (int qq = 1; qq < 4; ++qq) {
      float bq = __shfl(best, l0 + qq), sq = __shfl(second, l0 + qq);
      int   iq = __shfl(bi,   l0 + qq);
      if (bq > gb) { gs = fmaxf(gb, sq); gb = bq; gi = iq; }
      else         { gs = fmaxf(gs, bq); }
    }

    float conf = 0.0f; int cls = gi;
    if (__fsub_rn(gb, gs) < 1e-4f || gb > 5.0f) {
      // exact slow path (rare): identical to validated r1 80-sigmoid scan
      if (w == 0) {
        float bs = -INFINITY; int bj = 0;
        for (int kk = 0; kk < NCLS; ++kk) {
          int c = 64 + kk;
          float v = S[c * 64 + (idx ^ (((c >> 4) & 3) << 4))];
          float s2 = xla_sigmoid(v);
          if (s2 > bs) { bs = s2; bj = kk; }
        }
        conf = bs; cls = bj;
      }
    } else {
      conf = xla_sigmoid(gb);
    }

    if (w == 0) {
      float x1 = __fsub_rn(ax, lt0);
      float y1 = __fsub_rn(ay, lt1);
      float x2 = __fadd_rn(ax, lt2);
      float y2 = __fadd_rn(ay, lt3);
      float cx = __fmul_rn(__fadd_rn(x1, x2), 0.5f);
      float cy = __fmul_rn(__fadd_rn(y1, y2), 0.5f);
      float ww = __fsub_rn(x2, x1);
      float hh = __fsub_rn(y2, y1);
      int t = b * NA_TOT + lvlbase + a0blk + k * 64 + idx;
      oboxes[t] = make_float4(__fmul_rn(cx, stridef), __fmul_rn(cy, stridef),
                              __fmul_rn(ww, stridef), __fmul_rn(hh, stridef));
      conf = (conf > CONFTHR) ? conf : 0.0f;
      oconf[t] = conf;
      oclsf[t] = (float)cls;
    }
  };

  // ---- 2-phase pipeline: stage t+1 || compute t; counted drain per tile ----
  STAGE(0, 0);
  asm volatile("s_waitcnt vmcnt(0)" ::: "memory");
  __builtin_amdgcn_s_barrier();
  for (int k = 0; k < 4; ++k) {
    if (k < 3) STAGE((k + 1) & 1, k + 1);   // async, in flight during compute
    COMPUTE(k & 1, k);
    if (k < 3) {
      asm volatile("s_waitcnt vmcnt(0)" ::: "memory");
      __builtin_amdgcn_s_barrier();
    }
  }
}

// ---------------------------------------------------------------------------
// Kernel 2: per-image exact top-1024 select + rank (validated r5, unchanged).
// ---------------------------------------------------------------------------
struct __align__(16) K2Lds {
  unsigned long long sortkeys[SSORT];   // 16384 B (offset 0: 16B-aligned)
  unsigned confL[NA_TOT];               // 33600 B
  unsigned hist[16][257];               // 16448 B (per-wave, padded)
  unsigned tot[257];
  unsigned Tarr[257];
  unsigned long long alive[16];
  unsigned clsCnt[NCLS];
};                                      // ~69 KB

__global__ __launch_bounds__(1024) void yolo_select_kernel(
    const float4* __restrict__ boxes, const float* __restrict__ conf,
    const float* __restrict__ clsf,
    float* __restrict__ g_rowd, unsigned long long* __restrict__ g_alive,
    unsigned* __restrict__ g_clsc) {
  __shared__ K2Lds u;
  __shared__ unsigned s_need, s_prefix, s_found, s_B, s_scnt, s_cut, s_done;
  int b    = blockIdx.x;
  int tid  = threadIdx.x;
  int lane = tid & 63;
  int wv   = tid >> 6;
  const unsigned* confu = (const unsigned*)conf + (size_t)b * NA_TOT;

  // ---- P0: stage conf bits; zero outputs ----
  for (int i = tid; i < NA_TOT; i += 1024) u.confL[i] = confu[i];
  {
    float4 z4 = make_float4(0.f, 0.f, 0.f, 0.f);
    float4* gr = (float4*)(g_rowd + (size_t)b * 1024 * 8);
    for (int k = tid; k < 2048; k += 1024) gr[k] = z4;   // 1024 rows x 32 B
  }
  if (tid < NCLS) u.clsCnt[tid] = 0;
  if (tid < 16)   u.alive[tid]  = 0ull;
  if (tid == 0) { s_need = 1024; s_prefix = 0; s_cut = 0; s_done = 0; s_scnt = 0; }
  __syncthreads();

  // ---- P1: adaptive 8-bit radix descent (exact selcnt bound) ----
  for (int lv = 0; lv < 4; ++lv) {
    __syncthreads();
    if (s_done) break;                          // uniform
    for (int i = tid; i < 16 * 257; i += 1024) ((unsigned*)u.hist)[i] = 0;
    if (tid == 0) { s_found = 0; s_B = 0; }
    __syncthreads();
    unsigned pfx = s_prefix;
    for (int it = 0; it < 9; ++it) {
      int i = tid + it * 1024;
      unsigned c = (i < NA_TOT) ? u.confL[i] : 0u;
      bool in; unsigned bin;
      if (lv == 0)      { in = true;                bin = c >> 23; }
      else if (lv == 1) { in = ((c >> 23) == pfx);  bin = (c >> 15) & 0xFF; }
      else if (lv == 2) { in = ((c >> 15) == pfx);  bin = (c >> 7) & 0xFF; }
      else              { in = ((c >> 7)  == pfx);  bin = c & 0x7F; }
      bool act = (c != 0) && in;
      unsigned long long ab = __ballot(act);
      if (ab) {                                 // wave-uniform branch
        int fl = __ffsll(ab) - 1;
        unsigned fbin = __shfl(bin, fl);
        unsigned long long same = __ballot(act && (bin == fbin));
        if (same == ab) {                       // all active lanes same bin
          if (lane == fl) atomicAdd(&u.hist[wv][fbin], (unsigned)__popcll(ab));
        } else if (act) {
          atomicAdd(&u.hist[wv][bin], 1u);
        }
      }
    }
    __syncthreads();
    if (tid < 256) {                            // reduce 16 wave-hists
      unsigned s = 0;
      #pragma unroll
      for (int q = 0; q < 16; ++q) s += u.hist[q][tid];
      u.tot[tid] = s;
    }
    __syncthreads();
    if (tid < 64) {                             // suffix scan (4 chunks of 64)
      unsigned carry = 0;
      if (tid == 0) u.Tarr[256] = 0;
      for (int ch = 3; ch >= 0; --ch) {
        int bb = ch * 64 + tid;
        unsigned v = u.tot[bb];
        #pragma unroll
        for (int off = 1; off < 64; off <<= 1) {
          unsigned t2 = __shfl_down(v, off);
          if (tid + off < 64) v += t2;
        }
        u.Tarr[bb] = v + carry;
        carry += __shfl(v, 0);
      }
    }
    __syncthreads();
    unsigned need = s_need;
    if (tid < 256) {
      unsigned h = u.tot[tid];
      if (h > 0 && u.Tarr[tid + 1] < need && u.Tarr[tid + 1] + h >= need) {
        s_B = (unsigned)tid; s_found = 1;       // unique writer (T monotone)
      }
    }
    __syncthreads();
    if (tid == 0) {
      if (!s_found) { s_cut = 1; s_done = 1; }  // <1024 nonzero total (lv0)
      else {
        unsigned B = s_B;
        unsigned selcnt = (1024u - need) + u.Tarr[B];  // exact: committed + >=binB
        if (selcnt <= (unsigned)RANKCAP || lv == 3) {
          s_done = 1;
          if (lv == 0)      s_cut = B << 23;
          else if (lv == 1) s_cut = (s_prefix << 23) | (B << 15);
          else if (lv == 2) s_cut = (s_prefix << 15) | (B << 7);
          else              s_cut = (s_prefix << 7)  | B;
        } else {
          s_need   = need - u.Tarr[B + 1];
          s_prefix = (s_prefix << 8) | B;
        }
      }
    }
  }
  __syncthreads();

  // ---- P2: ballot-aggregated compact ----
  unsigned cut = s_cut;
  for (int it = 0; it < 9; ++it) {
    int i = tid + it * 1024;
    unsigned c = (i < NA_TOT) ? u.confL[i] : 0u;
    bool sel = (c != 0 && c >= cut);
    unsigned long long bal = __ballot(sel);
    unsigned base2 = 0;
    if (lane == 0 && bal) base2 = atomicAdd(&s_scnt, (unsigned)__popcll(bal));
    base2 = __shfl(base2, 0);
    if (sel) {
      unsigned p = base2 + (unsigned)__popcll(bal & ((1ull << lane) - 1ull));
      if (p < SSORT)
        u.sortkeys[p] = ((unsigned long long)c << 32) |
                        (unsigned long long)(0xFFFFFFFFu - (unsigned)i);
    }
  }
  __syncthreads();
  unsigned scnt = s_scnt; if (scnt > SSORT) scnt = SSORT;
  unsigned snp = (scnt + 1u) & ~1u;
  if (tid == 0 && (scnt & 1u)) u.sortkeys[scnt] = 0ull;  // pad for b128
  __syncthreads();

  // ---- P3: rank-by-count (b128 broadcast reads) + scatter to global ----
  for (unsigned e = tid; e < scnt; e += 1024) {
    unsigned long long mykey = u.sortkeys[e];
    unsigned r = 0;
    #pragma unroll 4
    for (unsigned j = 0; j < snp; j += 2) {
      ulonglong2 kk = *reinterpret_cast<const ulonglong2*>(&u.sortkeys[j]);
      r += (kk.x > mykey) ? 1u : 0u;
      r += (kk.y > mykey) ? 1u : 0u;
    }
    if (r < 1024) {                             // == lax.top_k truncation
      unsigned a = 0xFFFFFFFFu - (unsigned)(mykey & 0xFFFFFFFFull);
      float4 cb = boxes[(size_t)b * NA_TOT + a];
      float cls = clsf[(size_t)b * NA_TOT + a];
      float* rd = g_rowd + ((size_t)b * 1024 + r) * 8;
      rd[0] = cb.x; rd[1] = cb.y; rd[2] = cb.z; rd[3] = cb.w;
      rd[4] = __uint_as_float((unsigned)(mykey >> 32));
      rd[5] = cls;
      atomicOr(&u.alive[r >> 6], 1ull << (r & 63));
      atomicAdd(&u.clsCnt[(int)cls], 1u);
    }
  }
  __syncthreads();

  if (tid < 16)   g_alive[b * 16 + tid] = u.alive[tid];
  if (tid < NCLS) g_clsc[b * NCLS + tid] = u.clsCnt[tid];
}

// ---------------------------------------------------------------------------
// Kernel 3: per-image NMS (validated r5, unchanged): swizzled suppression-bit
// rows + single-wave greedy walk. Exact reference-scan semantics.
// ---------------------------------------------------------------------------
struct K3Lds {
  unsigned long long rows[1024][16];    // 131072 B, col-swizzled: phys = w^(r&15)
  float    rowdata[1024][6];            //  24576 B
  unsigned list[1024];                  //   4096 B
  unsigned clsCnt[NCLS];
  unsigned clsBase[NCLS];
  unsigned clsCur[NCLS];
  unsigned long long alive[16];
};                                      // ~160.9 KB

__global__ __launch_bounds__(1024) void yolo_nms_kernel(
    const float* __restrict__ g_rowd, const unsigned long long* __restrict__ g_alive,
    const unsigned* __restrict__ g_clsc, float* __restrict__ out) {
  __shared__ K3Lds u;
  __shared__ unsigned s_efinal;
  int b    = blockIdx.x;
  int tid  = threadIdx.x;
  int lane = tid & 63;

  // ---- load rowdata / alive / clsCnt; zero rows (linear = conflict-free) ----
  {
    const float4* gr = (const float4*)(g_rowd + ((size_t)b * 1024 + tid) * 8);
    float4 v0 = gr[0];
    float4 v1 = gr[1];
    u.rowdata[tid][0] = v0.x; u.rowdata[tid][1] = v0.y;
    u.rowdata[tid][2] = v0.z; u.rowdata[tid][3] = v0.w;
    u.rowdata[tid][4] = v1.x; u.rowdata[tid][5] = v1.y;
  }
  if (tid < 16)   u.alive[tid]  = g_alive[b * 16 + tid];
  if (tid < NCLS) u.clsCnt[tid] = g_clsc[b * NCLS + tid];
  {
    unsigned long long* flat = &u.rows[0][0];
    for (int k = tid; k < 1024 * 16; k += 1024) flat[k] = 0ull;
  }
  if (tid == 0) s_efinal = 0;
  __syncthreads();

  if (tid == 0) {
    unsigned acc = 0;
    for (int c2 = 0; c2 < NCLS; ++c2) {
      u.clsBase[c2] = acc; u.clsCur[c2] = acc; acc += u.clsCnt[c2];
    }
  }
  __syncthreads();

  // ---- per-class candidate lists ----
  bool valid = (u.alive[tid >> 6] >> (tid & 63)) & 1ull;
  float mycls = u.rowdata[tid][5];
  if (valid) {
    unsigned p = atomicAdd(&u.clsCur[(int)mycls], 1u);
    u.list[p] = (unsigned)tid;
  }
  __syncthreads();

  // ---- suppression-bit rows (same-class pairs; swizzled column writes) ----
  if (valid) {
    float bx0 = u.rowdata[tid][0], by0 = u.rowdata[tid][1];
    float bw0 = u.rowdata[tid][2], bh0 = u.rowdata[tid][3];
    int c = (int)mycls;
    unsigned base = u.clsBase[c], cnt = u.clsCnt[c];
    float off = __fmul_rn(mycls, 7680.0f);
    float hw  = __fmul_rn(bw0, 0.5f), hh = __fmul_rn(bh0, 0.5f);
    float wx1 = __fadd_rn(__fsub_rn(bx0, hw), off);
    float wy1 = __fadd_rn(__fsub_rn(by0, hh), off);
    float wx2 = __fadd_rn(__fadd_rn(bx0, hw), off);
    float wy2 = __fadd_rn(__fadd_rn(by0, hh), off);
    float a1  = __fmul_rn(__fsub_rn(wx2, wx1), __fsub_rn(wy2, wy1));
    int sw = tid & 15;
    for (unsigned l = 0; l < cnt; ++l) {
      int j = (int)u.list[base + l];
      float jx = u.rowdata[j][0], jy = u.rowdata[j][1];
      float jw = u.rowdata[j][2], jh = u.rowdata[j][3];
      float jhw = __fmul_rn(jw, 0.5f), jhh = __fmul_rn(jh, 0.5f);
      float jx1 = __fadd_rn(__fsub_rn(jx, jhw), off);
      float jy1 = __fadd_rn(__fsub_rn(jy, jhh), off);
      float jx2 = __fadd_rn(__fadd_rn(jx, jhw), off);
      float jy2 = __fadd_rn(__fadd_rn(jy, jhh), off);
      float ltx = fmaxf(wx1, jx1), lty = fmaxf(wy1, jy1);
      float rbx = fminf(wx2, jx2), rby = fminf(wy2, jy2);
      float iw = fmaxf(__fsub_rn(rbx, ltx), 0.0f);
      float ih = fmaxf(__fsub_rn(rby, lty), 0.0f);
      float inter = __fmul_rn(iw, ih);
      float a2 = __fmul_rn(__fsub_rn(jx2, jx1), __fsub_rn(jy2, jy1));
      float den = __fadd_rn(__fsub_rn(__fadd_rn(a1, a2), inter), 1e-7f);
      float iou = inter / den;
      if (iou > 0.7f)
        u.rows[tid][(j >> 6) ^ sw] |= (1ull << (j & 63));
    }
  }
  __syncthreads();

  // ---- single-wave greedy walk ----
  float* orow = out + (size_t)b * (MAXDET * 6);
  if (tid < 64) {
    unsigned long long am = (lane < 16) ? u.alive[lane] : 0ull;
    int e = 0;
    while (e < MAXDET) {
      unsigned long long bal = __ballot(am != 0ull);
      if (bal == 0ull) break;
      int f    = __ffsll((unsigned long long)bal) - 1;
      int myb  = __ffsll((unsigned long long)am) - 1;
      int bitp = __shfl(myb, f);
      int r    = f * 64 + bitp;                 // winner rank (uniform)
      if (lane < 6) orow[e * 6 + lane] = u.rowdata[r][lane];
      unsigned long long rowv =
          (lane < 16) ? u.rows[r][lane ^ (r & 15)] : 0ull;  // de-swizzle
      am &= ~rowv;      // winner self-suppresses via own row bit, as reference
      ++e;
    }
    if (tid == 0) s_efinal = (unsigned)e;
  }
  __syncthreads();

  // ---- zero-fill remaining output rows ----
  for (int i = (int)s_efinal * 6 + tid; i < MAXDET * 6; i += 1024)
    orow[i] = 0.0f;
}

extern "C" void kernel_launch(void* const* d_in, const int* in_sizes, int n_in,
                              void* d_out, int out_size, void* d_ws, size_t ws_size,
                              hipStream_t stream) {
  const float* f0 = (const float*)d_in[0];
  const float* f1 = (const float*)d_in[1];
  const float* f2 = (const float*)d_in[2];
  float* out = (float*)d_out;

  char* ws = (char*)d_ws;
  float4* boxes = (float4*)ws;                                       // 4,300,800
  float*  conf  = (float*)(ws + (size_t)NBATCH * NA_TOT * 16);       // 1,075,200
  float*  clsf  = (float*)(ws + (size_t)NBATCH * NA_TOT * 20);       // 1,075,200
  float*  rowd  = (float*)(ws + (size_t)NBATCH * NA_TOT * 24);       // 1,048,576
  unsigned long long* aliv =
      (unsigned long long*)(ws + (size_t)NBATCH * NA_TOT * 24 + 1048576);  // 4 KB
  unsigned* clsc =
      (unsigned*)(ws + (size_t)NBATCH * NA_TOT * 24 + 1048576 + 4096);     // 10 KB

  yolo_decode_kernel<<<NBATCH * BLKS_PER_IMG, 256, 0, stream>>>(
      f0, f1, f2, boxes, conf, clsf);
  yolo_select_kernel<<<NBATCH, 1024, 0, stream>>>(boxes, conf, clsf,
                                                  rowd, aliv, clsc);
  yolo_nms_kernel<<<NBATCH, 1024, 0, stream>>>(rowd, aliv, clsc, out);
}

// Round 9
// 147.453 us; speedup vs baseline: 1.2216x; 1.1535x over previous
//
#include <hip/hip_runtime.h>
#include <stdint.h>

#define NCLS    80
#define NA_TOT  8400     // 6400 + 1600 + 400
#define NBATCH  32
#define MAXDET  300
#define SSORT   2048
#define RANKCAP 1536
#define CONFTHR 0.001f
#define TILES_PER_IMG 132   // 100 (L0) + 25 (L1) + 7 (L2, clamped)

// ---------------------------------------------------------------------------
// Bit-exact reconstruction of XLA:CPU f32 exp (Eigen/Cephes pexp, no FMA) and
// logistic = 1/(1+exp(-x)). Validated absmax==0.0 rounds 1-8. DO NOT TOUCH.
// ---------------------------------------------------------------------------
__device__ __forceinline__ float xla_expf(float in) {
  const float exp_hi = 88.3762626647950f;
  const float exp_lo = -88.3762626647949f;
  const float LOG2EF = 1.44269504088896341f;
  const float C1 = 0.693359375f;
  const float C2 = -2.12194440e-4f;
  const float p0 = 1.9875691500E-4f, p1 = 1.3981999507E-3f, p2 = 8.3334519073E-3f;
  const float p3 = 4.1665795894E-2f, p4 = 1.6666665459E-1f, p5 = 5.0000001201E-1f;
  float x = fminf(fmaxf(in, exp_lo), exp_hi);
  float fx = floorf(__fadd_rn(__fmul_rn(x, LOG2EF), 0.5f));
  float tmp = __fmul_rn(C1, fx);
  float z   = __fmul_rn(C2, fx);
  x = __fsub_rn(x, tmp);
  x = __fsub_rn(x, z);
  float y = __fadd_rn(__fmul_rn(x, p0), p1);
  y = __fadd_rn(__fmul_rn(y, x), p2);
  y = __fadd_rn(__fmul_rn(y, x), p3);
  y = __fadd_rn(__fmul_rn(y, x), p4);
  y = __fadd_rn(__fmul_rn(y, x), p5);
  y = __fadd_rn(__fmul_rn(y, __fmul_rn(x, x)), x);
  y = __fadd_rn(1.0f, y);
  int m = (int)fx;
  float s = __uint_as_float((uint32_t)(m + 127) << 23);
  float r = __fmul_rn(y, s);
  return fmaxf(r, in);
}

__device__ __forceinline__ float xla_sigmoid(float v) {
  float e = xla_expf(-v);
  float den = __fadd_rn(1.0f, e);
  return 1.0f / den;
}

__device__ __forceinline__ void gload_lds16(const float* gp, float* lp) {
  __builtin_amdgcn_global_load_lds(
      (const __attribute__((address_space(1))) void*)gp,
      (__attribute__((address_space(3))) void*)lp, 16, 0, 0);
}

// ---------------------------------------------------------------------------
// Kernel 1: decode, occupancy-first. Block = 256 threads = 64 anchors x 4
// workers, ONE 36,864B LDS tile (4 blocks/CU = 16 waves/CU). Staging via
// global_load_lds with source-side XOR swizzle; COMPUTE identical to the
// validated r8 worker code (bit-exact r1 arithmetic).
// ---------------------------------------------------------------------------
__global__ __launch_bounds__(256) void yolo_decode_kernel(
    const float* __restrict__ f0, const float* __restrict__ f1,
    const float* __restrict__ f2,
    float4* __restrict__ oboxes, float* __restrict__ oconf,
    float* __restrict__ oclsf) {
  __shared__ float sm[144 * 64];                // 36,864 B -> 4 blocks/CU
  int bx  = blockIdx.x;
  int b   = bx / TILES_PER_IMG;
  int r   = bx - b * TILES_PER_IMG;
  int tid = threadIdx.x;
  int lane = tid & 63;
  int wv   = tid >> 6;

  const float* base; int Alvl, W, a0, lvlbase; float stridef;
  if (r < 100)      { base = f0 + (size_t)b * (144 * 6400); W = 80; Alvl = 6400;
                      a0 = r * 64; stridef = 8.0f; lvlbase = 0; }
  else if (r < 125) { base = f1 + (size_t)b * (144 * 1600); W = 40; Alvl = 1600;
                      a0 = (r - 100) * 64; stridef = 16.0f; lvlbase = 6400; }
  else              { base = f2 + (size_t)b * (144 * 400);  W = 20; Alvl = 400;
                      int aa = (r - 125) * 64; a0 = (aa + 64 <= 400) ? aa : 336;
                      stridef = 32.0f; lvlbase = 8000; }   // clamped overlap: benign

  // ---- STAGE: 9 x gload_lds(16B) per wave; source-side swizzle ----
  #pragma unroll
  for (int qq = 0; qq < 9; ++qq) {
    int chunk = wv * 9 + qq;                    // 0..35, 4 channels each
    int c     = chunk * 4 + (lane >> 4);
    int s     = (c >> 4) & 3;
    int idx4  = (lane & 15) ^ (s << 2);         // swizzle in 16B units
    const float* gp = base + (size_t)c * Alvl + a0 + idx4 * 4;
    gload_lds16(gp, sm + chunk * 256);
  }
  asm volatile("s_waitcnt vmcnt(0)" ::: "memory");
  __builtin_amdgcn_s_barrier();

  // ---- COMPUTE (validated r8 worker code; reads S[c*64 + idx^(s<<4)]) ----
  const float* S = sm;
  int idx = tid >> 2;                           // anchor in tile
  int w   = tid & 3;                            // worker
  int ai  = a0 + idx;
  float ax = __fadd_rn((float)(ai % W), 0.5f);
  float ay = __fadd_rn((float)(ai / W), 0.5f);

  int sidx = idx ^ (w << 4);                    // s(c)=w for c = w*16+rr
  float d[16];
  float mx = -INFINITY;
  #pragma unroll
  for (int rr = 0; rr < 16; ++rr) {
    d[rr] = S[(w * 16 + rr) * 64 + sidx];
    mx = fmaxf(mx, d[rr]);
  }
  float e[16]; float ssum = 0.0f;
  #pragma unroll
  for (int rr = 0; rr < 16; ++rr) {
    e[rr] = xla_expf(__fsub_rn(d[rr], mx));
    ssum = __fadd_rn(ssum, e[rr]);
  }
  float acc = 0.0f;
  #pragma unroll
  for (int rr = 0; rr < 16; ++rr) {
    float p = e[rr] / ssum;
    acc = __fadd_rn(acc, __fmul_rn(p, (float)rr));
  }

  int l0 = lane & ~3;
  float lt0 = __shfl(acc, l0 + 0);
  float lt1 = __shfl(acc, l0 + 1);
  float lt2 = __shfl(acc, l0 + 2);
  float lt3 = __shfl(acc, l0 + 3);

  float best = -INFINITY, second = -INFINITY; int bi = 0;
  #pragma unroll 5
  for (int kk = 0; kk < 20; ++kk) {
    int c = 64 + w * 20 + kk;
    float v = S[c * 64 + (idx ^ (((c >> 4) & 3) << 4))];
    if (v > best)        { second = best; best = v; bi = w * 20 + kk; }
    else if (v > second) { second = v; }
  }
  float gb = __shfl(best, l0 + 0), gs = __shfl(second, l0 + 0);
  int   gi = __shfl(bi,   l0 + 0);
  #pragma unroll
  for (int qq = 1; qq < 4; ++qq) {
    float bq = __shfl(best, l0 + qq), sq = __shfl(second, l0 + qq);
    int   iq = __shfl(bi,   l0 + qq);
    if (bq > gb) { gs = fmaxf(gb, sq); gb = bq; gi = iq; }
    else         { gs = fmaxf(gs, bq); }
  }

  float conf = 0.0f; int cls = gi;
  if (__fsub_rn(gb, gs) < 1e-4f || gb > 5.0f) {
    // exact slow path (rare): identical to validated r1 80-sigmoid scan
    if (w == 0) {
      float bs = -INFINITY; int bj = 0;
      for (int kk = 0; kk < NCLS; ++kk) {
        int c = 64 + kk;
        float v = S[c * 64 + (idx ^ (((c >> 4) & 3) << 4))];
        float s2 = xla_sigmoid(v);
        if (s2 > bs) { bs = s2; bj = kk; }
      }
      conf = bs; cls = bj;
    }
  } else {
    conf = xla_sigmoid(gb);
  }

  if (w == 0) {
    float x1 = __fsub_rn(ax, lt0);
    float y1 = __fsub_rn(ay, lt1);
    float x2 = __fadd_rn(ax, lt2);
    float y2 = __fadd_rn(ay, lt3);
    float cx = __fmul_rn(__fadd_rn(x1, x2), 0.5f);
    float cy = __fmul_rn(__fadd_rn(y1, y2), 0.5f);
    float ww = __fsub_rn(x2, x1);
    float hh = __fsub_rn(y2, y1);
    int t = b * NA_TOT + lvlbase + a0 + idx;
    oboxes[t] = make_float4(__fmul_rn(cx, stridef), __fmul_rn(cy, stridef),
                            __fmul_rn(ww, stridef), __fmul_rn(hh, stridef));
    conf = (conf > CONFTHR) ? conf : 0.0f;
    oconf[t] = conf;
    oclsf[t] = (float)cls;
  }
}

// ---------------------------------------------------------------------------
// Kernel 2 (fused select+NMS): adaptive radix descent (r5-validated) +
// ballot compact + bitonic-2048 (r2-validated) + swizzled bit-row NMS +
// single-wave walk (r5-validated). One block per image.
// ---------------------------------------------------------------------------
struct __align__(16) SelLds {
  union {
    struct {
      unsigned long long sortkeys[SSORT];   // 16384 B @ offset 0
      unsigned confL[NA_TOT];               // 33600 B
      unsigned hist[16][257];               // 16448 B
      unsigned tot[257];
      unsigned Tarr[257];
    } a;                                    // ~68.7 KB
    unsigned long long rows[1024][16];      // 131072 B (phase-B overlay)
  } u;
  float    rowdata[1024][6];                // 24576 B (disjoint from union)
  unsigned list[1024];                      //  4096 B
  unsigned clsCnt[NCLS];
  unsigned clsBase[NCLS];
  unsigned clsCur[NCLS];
  unsigned long long alive[16];
};                                          // 160,832 B total

__global__ __launch_bounds__(1024) void yolo_selectnms_kernel(
    const float4* __restrict__ boxes, const float* __restrict__ conf,
    const float* __restrict__ clsf, float* __restrict__ out) {
  __shared__ SelLds u;
  __shared__ unsigned s_need, s_prefix, s_found, s_B, s_scnt, s_cut, s_done,
                      s_efinal;
  int b    = blockIdx.x;
  int tid  = threadIdx.x;
  int lane = tid & 63;
  int wv   = tid >> 6;
  const unsigned* confu = (const unsigned*)conf + (size_t)b * NA_TOT;

  // ---- P0: stage conf bits; zero phase-B state outside the union ----
  for (int i = tid; i < NA_TOT; i += 1024) u.u.a.confL[i] = confu[i];
  #pragma unroll
  for (int q = 0; q < 6; ++q) u.rowdata[tid][q] = 0.0f;
  if (tid < NCLS) u.clsCnt[tid] = 0;
  if (tid < 16)   u.alive[tid]  = 0ull;
  if (tid == 0) { s_need = 1024; s_prefix = 0; s_cut = 0; s_done = 0;
                  s_scnt = 0; s_efinal = 0; }
  __syncthreads();

  // ---- P1: adaptive 8-bit radix descent (validated r5) ----
  for (int lv = 0; lv < 4; ++lv) {
    __syncthreads();
    if (s_done) break;                          // uniform
    for (int i = tid; i < 16 * 257; i += 1024) ((unsigned*)u.u.a.hist)[i] = 0;
    if (tid == 0) { s_found = 0; s_B = 0; }
    __syncthreads();
    unsigned pfx = s_prefix;
    for (int it = 0; it < 9; ++it) {
      int i = tid + it * 1024;
      unsigned c = (i < NA_TOT) ? u.u.a.confL[i] : 0u;
      bool in; unsigned bin;
      if (lv == 0)      { in = true;                bin = c >> 23; }
      else if (lv == 1) { in = ((c >> 23) == pfx);  bin = (c >> 15) & 0xFF; }
      else if (lv == 2) { in = ((c >> 15) == pfx);  bin = (c >> 7) & 0xFF; }
      else              { in = ((c >> 7)  == pfx);  bin = c & 0x7F; }
      bool act = (c != 0) && in;
      unsigned long long ab = __ballot(act);
      if (ab) {                                 // wave-uniform branch
        int fl = __ffsll(ab) - 1;
        unsigned fbin = __shfl(bin, fl);
        unsigned long long same = __ballot(act && (bin == fbin));
        if (same == ab) {                       // all active lanes same bin
          if (lane == fl) atomicAdd(&u.u.a.hist[wv][fbin], (unsigned)__popcll(ab));
        } else if (act) {
          atomicAdd(&u.u.a.hist[wv][bin], 1u);
        }
      }
    }
    __syncthreads();
    if (tid < 256) {                            // reduce 16 wave-hists
      unsigned s = 0;
      #pragma unroll
      for (int q = 0; q < 16; ++q) s += u.u.a.hist[q][tid];
      u.u.a.tot[tid] = s;
    }
    __syncthreads();
    if (tid < 64) {                             // suffix scan (4 chunks of 64)
      unsigned carry = 0;
      if (tid == 0) u.u.a.Tarr[256] = 0;
      for (int ch = 3; ch >= 0; --ch) {
        int bb = ch * 64 + tid;
        unsigned v = u.u.a.tot[bb];
        #pragma unroll
        for (int off = 1; off < 64; off <<= 1) {
          unsigned t2 = __shfl_down(v, off);
          if (tid + off < 64) v += t2;
        }
        u.u.a.Tarr[bb] = v + carry;
        carry += __shfl(v, 0);
      }
    }
    __syncthreads();
    unsigned need = s_need;
    if (tid < 256) {
      unsigned h = u.u.a.tot[tid];
      if (h > 0 && u.u.a.Tarr[tid + 1] < need && u.u.a.Tarr[tid + 1] + h >= need) {
        s_B = (unsigned)tid; s_found = 1;       // unique writer (T monotone)
      }
    }
    __syncthreads();
    if (tid == 0) {
      if (!s_found) { s_cut = 1; s_done = 1; }  // <1024 nonzero total (lv0)
      else {
        unsigned B = s_B;
        unsigned selcnt = (1024u - need) + u.u.a.Tarr[B];  // exact count >= cut
        if (selcnt <= (unsigned)RANKCAP || lv == 3) {
          s_done = 1;
          if (lv == 0)      s_cut = B << 23;
          else if (lv == 1) s_cut = (s_prefix << 23) | (B << 15);
          else if (lv == 2) s_cut = (s_prefix << 15) | (B << 7);
          else              s_cut = (s_prefix << 7)  | B;
        } else {
          s_need   = need - u.u.a.Tarr[B + 1];
          s_prefix = (s_prefix << 8) | B;
        }
      }
    }
  }
  __syncthreads();

  // ---- P2: ballot-aggregated compact + zero-pad to SSORT ----
  unsigned cut = s_cut;
  for (int it = 0; it < 9; ++it) {
    int i = tid + it * 1024;
    unsigned c = (i < NA_TOT) ? u.u.a.confL[i] : 0u;
    bool sel = (c != 0 && c >= cut);
    unsigned long long bal = __ballot(sel);
    unsigned base2 = 0;
    if (lane == 0 && bal) base2 = atomicAdd(&s_scnt, (unsigned)__popcll(bal));
    base2 = __shfl(base2, 0);
    if (sel) {
      unsigned p = base2 + (unsigned)__popcll(bal & ((1ull << lane) - 1ull));
      if (p < SSORT)
        u.u.a.sortkeys[p] = ((unsigned long long)c << 32) |
                            (unsigned long long)(0xFFFFFFFFu - (unsigned)i);
    }
  }
  __syncthreads();
  {
    unsigned scnt = s_scnt; if (scnt > SSORT) scnt = SSORT;
    for (unsigned p = scnt + tid; p < SSORT; p += 1024) u.u.a.sortkeys[p] = 0ull;
  }
  __syncthreads();

  // ---- P3: bitonic sort 2048 (ascending; validated r2 index math) ----
  for (int k = 2; k <= SSORT; k <<= 1) {
    for (int j = k >> 1; j > 0; j >>= 1) {
      int i = ((tid & ~(j - 1)) << 1) | (tid & (j - 1));
      int l = i | j;
      unsigned long long A = u.u.a.sortkeys[i], Bv = u.u.a.sortkeys[l];
      bool up = ((i & k) == 0);
      if (up ? (A > Bv) : (A < Bv)) { u.u.a.sortkeys[i] = Bv; u.u.a.sortkeys[l] = A; }
      __syncthreads();
    }
  }

  // ---- P4: gather rank tid (== lax.top_k row tid); fill rowdata ----
  {
    unsigned long long key = u.u.a.sortkeys[SSORT - 1 - tid];
    bool valid = (key >> 32) != 0ull;
    if (valid) {
      unsigned a = 0xFFFFFFFFu - (unsigned)(key & 0xFFFFFFFFull);
      float4 cb = boxes[(size_t)b * NA_TOT + a];
      float cls = clsf[(size_t)b * NA_TOT + a];
      u.rowdata[tid][0] = cb.x;
      u.rowdata[tid][1] = cb.y;
      u.rowdata[tid][2] = cb.z;
      u.rowdata[tid][3] = cb.w;
      u.rowdata[tid][4] = __uint_as_float((unsigned)(key >> 32));
      u.rowdata[tid][5] = cls;
      atomicOr(&u.alive[tid >> 6], 1ull << (tid & 63));
      atomicAdd(&u.clsCnt[(int)cls], 1u);
    }
  }
  __syncthreads();      // sortkeys dead; union becomes rows

  // ---- P5: zero rows; class bases; class lists ----
  #pragma unroll
  for (int q = 0; q < 16; ++q) u.u.rows[tid][q] = 0ull;
  if (tid == 0) {
    unsigned acc = 0;
    for (int c2 = 0; c2 < NCLS; ++c2) {
      u.clsBase[c2] = acc; u.clsCur[c2] = acc; acc += u.clsCnt[c2];
    }
  }
  __syncthreads();
  bool valid = (u.alive[tid >> 6] >> (tid & 63)) & 1ull;
  float mycls = u.rowdata[tid][5];
  if (valid) {
    unsigned p = atomicAdd(&u.clsCur[(int)mycls], 1u);
    u.list[p] = (unsigned)tid;
  }
  __syncthreads();

  // ---- P6: suppression-bit rows (same-class pairs; swizzled columns) ----
  if (valid) {
    float bx0 = u.rowdata[tid][0], by0 = u.rowdata[tid][1];
    float bw0 = u.rowdata[tid][2], bh0 = u.rowdata[tid][3];
    int c = (int)mycls;
    unsigned base = u.clsBase[c], cnt = u.clsCnt[c];
    float off = __fmul_rn(mycls, 7680.0f);
    float hw  = __fmul_rn(bw0, 0.5f), hh = __fmul_rn(bh0, 0.5f);
    float wx1 = __fadd_rn(__fsub_rn(bx0, hw), off);
    float wy1 = __fadd_rn(__fsub_rn(by0, hh), off);
    float wx2 = __fadd_rn(__fadd_rn(bx0, hw), off);
    float wy2 = __fadd_rn(__fadd_rn(by0, hh), off);
    float a1  = __fmul_rn(__fsub_rn(wx2, wx1), __fsub_rn(wy2, wy1));
    int sw = tid & 15;
    for (unsigned l = 0; l < cnt; ++l) {
      int j = (int)u.list[base + l];
      float jx = u.rowdata[j][0], jy = u.rowdata[j][1];
      float jw = u.rowdata[j][2], jh = u.rowdata[j][3];
      float jhw = __fmul_rn(jw, 0.5f), jhh = __fmul_rn(jh, 0.5f);
      float jx1 = __fadd_rn(__fsub_rn(jx, jhw), off);
      float jy1 = __fadd_rn(__fsub_rn(jy, jhh), off);
      float jx2 = __fadd_rn(__fadd_rn(jx, jhw), off);
      float jy2 = __fadd_rn(__fadd_rn(jy, jhh), off);
      float ltx = fmaxf(wx1, jx1), lty = fmaxf(wy1, jy1);
      float rbx = fminf(wx2, jx2), rby = fminf(wy2, jy2);
      float iw = fmaxf(__fsub_rn(rbx, ltx), 0.0f);
      float ih = fmaxf(__fsub_rn(rby, lty), 0.0f);
      float inter = __fmul_rn(iw, ih);
      float a2 = __fmul_rn(__fsub_rn(jx2, jx1), __fsub_rn(jy2, jy1));
      float den = __fadd_rn(__fsub_rn(__fadd_rn(a1, a2), inter), 1e-7f);
      float iou = inter / den;
      if (iou > 0.7f)
        u.u.rows[tid][(j >> 6) ^ sw] |= (1ull << (j & 63));
    }
  }
  __syncthreads();

  // ---- P7: single-wave greedy walk (exact reference-scan semantics) ----
  float* orow = out + (size_t)b * (MAXDET * 6);
  if (tid < 64) {
    unsigned long long am = (lane < 16) ? u.alive[lane] : 0ull;
    int e = 0;
    while (e < MAXDET) {
      unsigned long long bal = __ballot(am != 0ull);
      if (bal == 0ull) break;
      int f    = __ffsll((unsigned long long)bal) - 1;
      int myb  = __ffsll((unsigned long long)am) - 1;
      int bitp = __shfl(myb, f);
      int r    = f * 64 + bitp;                 // winner rank (uniform)
      if (lane < 6) orow[e * 6 + lane] = u.rowdata[r][lane];
      unsigned long long rowv =
          (lane < 16) ? u.u.rows[r][lane ^ (r & 15)] : 0ull;  // de-swizzle
      am &= ~rowv;      // winner self-suppresses via own row bit, as reference
      ++e;
    }
    if (tid == 0) s_efinal = (unsigned)e;
  }
  __syncthreads();

  // ---- P8: zero-fill remaining output rows ----
  for (int i = (int)s_efinal * 6 + tid; i < MAXDET * 6; i += 1024)
    orow[i] = 0.0f;
}

extern "C" void kernel_launch(void* const* d_in, const int* in_sizes, int n_in,
                              void* d_out, int out_size, void* d_ws, size_t ws_size,
                              hipStream_t stream) {
  const float* f0 = (const float*)d_in[0];
  const float* f1 = (const float*)d_in[1];
  const float* f2 = (const float*)d_in[2];
  float* out = (float*)d_out;

  char* ws = (char*)d_ws;
  float4* boxes = (float4*)ws;                                   // 32*8400*16 B
  float*  conf  = (float*)(ws + (size_t)NBATCH * NA_TOT * 16);   // 32*8400*4 B
  float*  clsf  = (float*)(ws + (size_t)NBATCH * NA_TOT * 20);   // 32*8400*4 B

  yolo_decode_kernel<<<NBATCH * TILES_PER_IMG, 256, 0, stream>>>(
      f0, f1, f2, boxes, conf, clsf);
  yolo_selectnms_kernel<<<NBATCH, 1024, 0, stream>>>(boxes, conf, clsf, out);
}